// Round 25
// baseline (44.383 us; speedup 1.0000x reference)
//
#include <hip/hip_runtime.h>

// Conv2d 5x5, C=3, O=1, stride 1, pad 2, N=256, H=W=224, +bias.
// R25: BARRIER-FREE wave-autonomous pipeline with counted vmcnt (T4).
//   R21/R24 plateau at ~42.4us vs ~22us max-pipe floor = barrier-phase
//   serialization. Waves only share staged rows shallowly (wave w reads LDS
//   rows 4w..4w+7), so: give each wave a PRIVATE 8-row x 2-buffer staging
//   region -> no __syncthreads anywhere. Per-wave schedule:
//     S(ch0->A) S(ch1->B) vmcnt(8) fix0 C(ch0,A)
//     lgkmcnt(0) sched_barrier S(ch2->A) vmcnt(8) fix1 C(ch1,B)
//     vmcnt(0) fix0 C(ch2,A) store
//   vmcnt counts are exact: every stage issues EXACTLY 8 gl_lds16 (OOB rows
//   clamp the source address; the garbage is zeroed by ds_write after the
//   landing waitcnt, before compute - DS ops are in-order per wave).
//   Cost: 2x stage-read amplification (adjacent waves' 4-row halo overlap;
//   absorbed by L2/L3) and 29696 B/block -> 5 blocks/CU = 10 waves/CU,
//   each with 8-16 loads perpetually in flight (no barrier ever drains them).
// Kept: RST=232 rows (+4-dword shift), LDS-resident x-pads (dwords
// {2,3,228,229} zeroed once per wave), 7-wide x 2-tall full-lane mapping,
// gl_lds16 staging (wave-uniform dest, lane<56), XCD swizzle, no
// launch_bounds min-arg.

namespace {

constexpr int Hc = 224, Wc = 224, Cc = 3;
constexpr int HW = Hc * Wc;
constexpr int CHW = Cc * HW;
constexpr int RST = 232;              // LDS row stride (dwords); 232%32 = 8
constexpr int SR = 8;                 // staged rows per wave per buffer
constexpr int BUFD = SR * RST;        // 1856 dwords = 7424 B per buffer
constexpr int BLK = 128;              // 2 independent waves per block
constexpr int SLICES = 56;            // 4-output-row slices per image (224/4)

__device__ __forceinline__ void gl_lds16(const float* g, float* l) {
  __builtin_amdgcn_global_load_lds(
      (const __attribute__((address_space(1))) void*)g,
      (__attribute__((address_space(3))) void*)l, 16, 0, 0);
}

__global__ __launch_bounds__(BLK) void conv5x5_r25(
    const float* __restrict__ x, const float* __restrict__ wl,
    const float* __restrict__ bptr, float* __restrict__ out) {
  __shared__ __align__(16) float sm[2 * 2 * BUFD];   // 2 waves x 2 bufs

  const int tid = threadIdx.x;
  const int lane = tid & 63;
  const int wv = tid >> 6;                 // 0..1
  float* mylds = sm + wv * (2 * BUFD);     // this wave's private region

  // Bijective XCD swizzle: 7168 = 8 * 896.
  const int cpx = gridDim.x >> 3;
  const int bid = (blockIdx.x & 7) * cpx + (blockIdx.x >> 3);
  const int sid = bid * 2 + wv;            // global slice id (0..14335)
  const int n = sid / SLICES;              // image
  const int slice = sid % SLICES;          // 4-row slice within image
  const int oy0 = slice * 4;               // first output row

  // Weights: wave-uniform, compile-time offsets -> SGPRs.
  float w[Cc][5][5];
#pragma unroll
  for (int c = 0; c < Cc; ++c)
#pragma unroll
    for (int i = 0; i < 25; ++i) w[c][i / 5][i % 5] = wl[c * 25 + i];
  const float bias = bptr[0];

  const float* xn = x + (size_t)n * CHW;
  float* outn = out + (size_t)n * HW;

  // Compute roles within the wave: 64 lanes = 32 col-groups (7 wide) x 2
  // row-groups (2 rows each -> 4 output rows). Window base = LDS dword
  // 7g+2 (global dword j lives at LDS j+4; window = global 7g-2..7g+8).
  const int g = lane & 31;
  const int tg = lane >> 5;                // 0..1
  const int rdo = g * 7 + 2;

  float acc[2][7];                         // 2 rows x 7 cols, static indexed

  // ---- one-time x-pad zeroing (per wave, private region): 64 lanes cover
  // 2 bufs x 8 rows x dwords {2,3,228,229} exactly. DS ops are in-order per
  // wave -> later ds_reads see the zeros without a fence.
  {
    const int bu = lane >> 5;              // 0..1
    const int rr = (lane & 31) >> 2;       // 0..7
    const int j = lane & 3;                // 0..3
    mylds[bu * BUFD + rr * RST + (j < 2 ? 2 + j : 226 + j)] = 0.f;
  }

  // Stage channel CH into buffer B: 8 rows, gy = oy0-2+r, ADDRESS-CLAMPED so
  // exactly 8 gl_lds16 always issue (vmcnt arithmetic stays exact). Garbage
  // in OOB rows is zeroed by FIX_OOB after the landing waitcnt.
#define STAGE_W(CH, B)                                                        \
  do {                                                                        \
    const float* gch_ = xn + (size_t)(CH) * HW;                               \
    float* dst_ = mylds + (B) * BUFD;                                         \
    _Pragma("unroll") for (int r_ = 0; r_ < SR; ++r_) {                       \
      const int gy_ = oy0 - 2 + r_;                                           \
      const int yc_ = gy_ < 0 ? 0 : (gy_ > Hc - 1 ? Hc - 1 : gy_);            \
      if (lane < 56)                                                          \
        gl_lds16(gch_ + (size_t)yc_ * Wc + lane * 4, dst_ + r_ * RST + 4);    \
    }                                                                         \
  } while (0)

  // Zero the y-pad rows of buffer B (only slices 0 and 55 have any).
  // ds_write covers dwords 4..227 (lane<56); pads 2,3,228,229 already zero.
#define FIX_OOB(B)                                                            \
  do {                                                                        \
    if (slice == 0) {                                                         \
      if (lane < 56) {                                                        \
        *(float4*)(mylds + (B) * BUFD + 0 * RST + 4 + lane * 4) =             \
            make_float4(0.f, 0.f, 0.f, 0.f);                                  \
        *(float4*)(mylds + (B) * BUFD + 1 * RST + 4 + lane * 4) =             \
            make_float4(0.f, 0.f, 0.f, 0.f);                                  \
      }                                                                       \
    } else if (slice == SLICES - 1) {                                         \
      if (lane < 56) {                                                        \
        *(float4*)(mylds + (B) * BUFD + 6 * RST + 4 + lane * 4) =             \
            make_float4(0.f, 0.f, 0.f, 0.f);                                  \
        *(float4*)(mylds + (B) * BUFD + 7 * RST + 4 + lane * 4) =             \
            make_float4(0.f, 0.f, 0.f, 0.f);                                  \
      }                                                                       \
    }                                                                         \
  } while (0)

  // Compute channel CH from buffer B. Thread reads LDS rows tg*2 + jj,
  // jj=0..5; output local row lr = tg*2 + r_ taps ky = jj - r_.
  // Window = raw 11-dword read (x-pads are real zeros).
#define COMPUTE_W(CH, B)                                                      \
  do {                                                                        \
    constexpr int ch_ = (CH);                                                 \
    const float* bp_ = mylds + (B) * BUFD;                                    \
    if (ch_ == 0) {                                                           \
      _Pragma("unroll") for (int r_ = 0; r_ < 2; ++r_)                        \
          _Pragma("unroll") for (int c_ = 0; c_ < 7; ++c_)                    \
              acc[r_][c_] = 0.f;                                              \
    }                                                                         \
    _Pragma("unroll") for (int jj_ = 0; jj_ < 6; ++jj_) {                     \
      const float* rp_ = bp_ + (tg * 2 + jj_) * RST + rdo;                    \
      float win_[11];                                                         \
      _Pragma("unroll") for (int j_ = 0; j_ < 11; ++j_) win_[j_] = rp_[j_];   \
      _Pragma("unroll") for (int r_ = 0; r_ < 2; ++r_) {                      \
        if (r_ <= jj_ && jj_ - r_ <= 4) {                                     \
          _Pragma("unroll") for (int kx_ = 0; kx_ < 5; ++kx_) {               \
            const float wv_ = w[ch_][jj_ - r_][kx_];                          \
            _Pragma("unroll") for (int c_ = 0; c_ < 7; ++c_) {                \
              acc[r_][c_] = fmaf(win_[c_ + kx_], wv_, acc[r_][c_]);           \
            }                                                                 \
          }                                                                   \
        }                                                                     \
      }                                                                       \
    }                                                                         \
    if (ch_ == 2) {                                                           \
      _Pragma("unroll") for (int r_ = 0; r_ < 2; ++r_) {                      \
        const int gy_ = oy0 + tg * 2 + r_;                                    \
        float* op_ = outn + (size_t)gy_ * Wc + g * 7;                         \
        _Pragma("unroll") for (int c_ = 0; c_ < 7; ++c_)                      \
            op_[c_] = acc[r_][c_] + bias;                                     \
      }                                                                       \
    }                                                                         \
  } while (0)

  // ---- barrier-free per-wave pipeline, counted vmcnt ----
  STAGE_W(0, 0);                                    // vmcnt: 8
  STAGE_W(1, 1);                                    // vmcnt: 16
  asm volatile("s_waitcnt vmcnt(8)" ::: "memory");  // ch0 landed
  FIX_OOB(0);
  COMPUTE_W(0, 0);
  // buf0 ds_reads must retire before gl_lds16 overwrites buf0:
  asm volatile("s_waitcnt lgkmcnt(0)" ::: "memory");
  __builtin_amdgcn_sched_barrier(0);
  STAGE_W(2, 0);                                    // vmcnt: <=16
  asm volatile("s_waitcnt vmcnt(8)" ::: "memory");  // ch1 landed
  FIX_OOB(1);
  COMPUTE_W(1, 1);
  asm volatile("s_waitcnt vmcnt(0)" ::: "memory");  // ch2 landed
  FIX_OOB(0);
  COMPUTE_W(2, 0);

#undef STAGE_W
#undef FIX_OOB
#undef COMPUTE_W
}

}  // namespace

extern "C" void kernel_launch(void* const* d_in, const int* in_sizes, int n_in,
                              void* d_out, int out_size, void* d_ws, size_t ws_size,
                              hipStream_t stream) {
  const float* x  = (const float*)d_in[0];   // [N,3,224,224] f32
  const float* wl = (const float*)d_in[1];   // [1,75] f32
  const float* b  = (const float*)d_in[2];   // [1] f32
  float* out = (float*)d_out;                // [N,224,224] f32

  const int N = out_size / HW;               // 256
  const int nblk = N * SLICES / 2;           // 7168 = 8 * 896
  conv5x5_r25<<<nblk, BLK, 0, stream>>>(x, wl, b, out);
}